// Round 7
// baseline (180.281 us; speedup 1.0000x reference)
//
#include <hip/hip_runtime.h>

#define HH 256
#define WW 256
#define BB 4
#define HW (HH*WW)
#define N_ITER 20
#define EPSV 1e-8f

#define FUSE 4
#define TX 32
#define TY 16
#define HALO (2*FUSE)            // 8
#define EXTX (TX + 2*HALO)       // 48
#define EXTY (TY + 2*HALO)       // 32
#define EPAD 60                  // row stride (floats): 240B, 16B-aligned
#define COFF 4                   // column offset: x-1 edge reads stay in-bounds & aligned
#define QXN  (EXTX/4)            // 12 quads per row
#define NTHR (EXTY*QXN)          // 384 threads = 6 waves

__device__ __forceinline__ float ldz(const float* __restrict__ p, int y, int x) {
    if ((unsigned)y < HH && (unsigned)x < WW) return p[y*WW + x];
    return 0.0f;
}
__device__ __forceinline__ float sobelXg(const float* __restrict__ p, int y, int x) {
    return -ldz(p,y-1,x-1) + ldz(p,y-1,x+1)
         - 2.0f*ldz(p,y,x-1) + 2.0f*ldz(p,y,x+1)
         - ldz(p,y+1,x-1) + ldz(p,y+1,x+1);
}
__device__ __forceinline__ float sobelYg(const float* __restrict__ p, int y, int x) {
    return -ldz(p,y-1,x-1) - 2.0f*ldz(p,y-1,x) - ldz(p,y-1,x+1)
          + ldz(p,y+1,x-1) + 2.0f*ldz(p,y+1,x) + ldz(p,y+1,x+1);
}

__global__ void tvl1_init(const float* __restrict__ xin, float* __restrict__ u,
                          float* __restrict__ p1, float* __restrict__ p2,
                          float* __restrict__ gx, float* __restrict__ gy,
                          float* __restrict__ rc) {
    int x = blockIdx.x*blockDim.x + threadIdx.x;
    int y = blockIdx.y*blockDim.y + threadIdx.y;
    int b = blockIdx.z;
    int idx = y*WW + x;
    int pb = b*2*HW;
    const float* im1 = xin + pb + HW;     // channel 1
    float i1 = im1[idx];
    rc[b*HW + idx] = i1 - xin[pb + idx];  // im1 - im0
    gx[b*HW + idx] = sobelXg(im1, y, x);
    gy[b*HW + idx] = sobelYg(im1, y, x);
    u[pb + idx] = 0.0f;  u[pb + HW + idx] = 0.0f;
    p1[pb + idx] = 0.0f; p1[pb + HW + idx] = 0.0f;
    p2[pb + idx] = 0.0f; p2[pb + HW + idx] = 0.0f;
}

// v[0..5] = s[y][COFF + x-1 .. COFF + x+4]   (x multiple of 4; all in-bounds)
__device__ __forceinline__ void ldrow(const float (*__restrict__ s)[EPAD], int y, int x, float* v) {
    const float4 m = *(const float4*)&s[y][COFF + x];   // 16B-aligned
    v[0] = s[y][COFF + x - 1];
    v[1] = m.x; v[2] = m.y; v[3] = m.z; v[4] = m.w;
    v[5] = s[y][COFF + x + 4];
}

template<int LAST>
__global__ __launch_bounds__(NTHR, 3)   // cap VGPR<=170: 2 blocks/CU co-resident (92KB LDS, 12 waves)
void tvl1_fused(float* __restrict__ u,
                float* __restrict__ p1, float* __restrict__ p2,
                const float* __restrict__ gxc, const float* __restrict__ gyc,
                const float* __restrict__ rcc,
                const float* __restrict__ lam, const float* __restrict__ tau,
                const float* __restrict__ the) {
    __shared__ float su0[EXTY][EPAD], su1[EXTY][EPAD];
    __shared__ float sp10[EXTY][EPAD], sp11[EXTY][EPAD];
    __shared__ float sp20[EXTY][EPAD], sp21[EXTY][EPAD];   // 6 * 32*60*4B = 46.1 KB

    const int tid = threadIdx.x;
    const int qy = tid / QXN;                // 0..31 (compile-time divisor)
    const int qx = (tid - qy*QXN) * 4;       // 0,4,...,44
    const int b  = blockIdx.z;
    const int ox = blockIdx.x*TX - HALO;
    const int oy = blockIdx.y*TY - HALO;
    const int pb = b*2*HW, cb = b*HW;
    const float theta = the[0];
    const float tl = theta * lam[0];
    const float r = tau[0] / theta;

    const int gyy = oy + qy;
    const int gxx = ox + qx;
    // quads are 4-aligned and W%4==0 -> a quad never straddles the image edge
    const bool inq = ((unsigned)gyy < HH) && ((unsigned)gxx < WW);
    // out-of-image quads stay exactly 0 (SAME padding); rows 0 / EXTY-1 never
    // update (LDS bounds). No ring masking: values outside ring h are never
    // read by any pixel that remains valid (1 ring per half-step, halo=8=NH).
    const bool act = inq && (qy >= 1) && (qy < EXTY-1);
    const int gi = gyy*WW + gxx;

    float ru0[4], ru1[4], rp10[4], rp11[4], rp20[4], rp21[4];
    float rgx[4], rgy[4], rrc[4];

    // ---- stage: regs hold this quad's state; LDS holds neighbor-visible copies ----
    if (inq) {
        *(float4*)ru0  = *(const float4*)&u  [pb + gi];
        *(float4*)ru1  = *(const float4*)&u  [pb + HW + gi];
        *(float4*)rp10 = *(const float4*)&p1 [pb + gi];
        *(float4*)rp11 = *(const float4*)&p1 [pb + HW + gi];
        *(float4*)rp20 = *(const float4*)&p2 [pb + gi];
        *(float4*)rp21 = *(const float4*)&p2 [pb + HW + gi];
        *(float4*)rgx  = *(const float4*)&gxc[cb + gi];
        *(float4*)rgy  = *(const float4*)&gyc[cb + gi];
        *(float4*)rrc  = *(const float4*)&rcc[cb + gi];
    } else {
        #pragma unroll
        for (int j = 0; j < 4; ++j) {
            ru0[j]=ru1[j]=rp10[j]=rp11[j]=rp20[j]=rp21[j]=0.f;
            rgx[j]=rgy[j]=rrc[j]=0.f;
        }
    }

    *(float4*)&su0 [qy][COFF+qx] = *(float4*)ru0;
    *(float4*)&su1 [qy][COFF+qx] = *(float4*)ru1;
    *(float4*)&sp10[qy][COFF+qx] = *(float4*)rp10;
    *(float4*)&sp11[qy][COFF+qx] = *(float4*)rp11;
    *(float4*)&sp20[qy][COFF+qx] = *(float4*)rp20;
    *(float4*)&sp21[qy][COFF+qx] = *(float4*)rp21;
    // zero the only pad columns ever read (col 3 = left edge, col 52 = right edge)
    if (tid < 2*EXTY) {
        int row = tid >> 1, col = (tid & 1) ? 3 : 52;
        su0[row][col] = 0.f;  su1[row][col] = 0.f;
        sp10[row][col] = 0.f; sp11[row][col] = 0.f;
        sp20[row][col] = 0.f; sp21[row][col] = 0.f;
    }
    __syncthreads();

    #pragma unroll
    for (int it = 0; it < FUSE; ++it) {
        // ---- u half-step: pointwise u from regs, p neighbors from LDS (writes su* only) ----
        if (act) {
            float A[6], B[6], C[6], D[6], E[6];
            float div0[4], div1[4];
            {   // channel 0 divergence
                ldrow(sp10, qy-1, qx, A); ldrow(sp10, qy, qx, B); ldrow(sp10, qy+1, qx, C);
                ldrow(sp20, qy-1, qx, D); ldrow(sp20, qy+1, qx, E);   // SBY middle row weight 0
                #pragma unroll
                for (int j = 0; j < 4; ++j)
                    div0[j] = (-A[j] + A[j+2] - 2.f*B[j] + 2.f*B[j+2] - C[j] + C[j+2])
                            + (-D[j] - 2.f*D[j+1] - D[j+2] + E[j] + 2.f*E[j+1] + E[j+2]);
            }
            {   // channel 1 divergence (reuse window registers)
                ldrow(sp11, qy-1, qx, A); ldrow(sp11, qy, qx, B); ldrow(sp11, qy+1, qx, C);
                ldrow(sp21, qy-1, qx, D); ldrow(sp21, qy+1, qx, E);
                #pragma unroll
                for (int j = 0; j < 4; ++j)
                    div1[j] = (-A[j] + A[j+2] - 2.f*B[j] + 2.f*B[j+2] - C[j] + C[j+2])
                            + (-D[j] - 2.f*D[j+1] - D[j+2] + E[j] + 2.f*E[j+1] + E[j+2]);
            }
            #pragma unroll
            for (int j = 0; j < 4; ++j) {
                float g_x = rgx[j], g_y = rgy[j];
                float ng  = g_x*g_x + g_y*g_y + EPSV;
                float rho = rrc[j] + g_x*ru0[j] + g_y*ru1[j];
                float th  = tl * ng;
                float sgn = (rho > 0.f) ? 1.f : ((rho < 0.f) ? -1.f : 0.f);
                float d   = (fabsf(rho) < th) ? (rho / ng) : (tl * sgn);
                ru0[j] = ru0[j] - d*g_x + theta*div0[j];
                ru1[j] = ru1[j] - d*g_y + theta*div1[j];
            }
            *(float4*)&su0[qy][COFF+qx] = *(float4*)ru0;
            *(float4*)&su1[qy][COFF+qx] = *(float4*)ru1;
        }
        __syncthreads();

        if (LAST && it == FUSE-1) break;    // 20th p-update never feeds the output

        // ---- p half-step: pointwise p from regs, u neighbors from LDS (writes sp* only) ----
        if (act) {
            float A[6], B[6], C[6];
            {   // channel 0
                ldrow(su0, qy-1, qx, A); ldrow(su0, qy, qx, B); ldrow(su0, qy+1, qx, C);
                #pragma unroll
                for (int j = 0; j < 4; ++j) {
                    float g1x = -A[j] + A[j+2] - 2.f*B[j] + 2.f*B[j+2] - C[j] + C[j+2];
                    float g1y = -A[j] - 2.f*A[j+1] - A[j+2] + C[j] + 2.f*C[j+1] + C[j+2];
                    float inv1 = 1.f / (1.f + r*(fabsf(g1x) + fabsf(g1y)));
                    rp10[j] = (rp10[j] + r*g1x) * inv1;
                    rp11[j] = (rp11[j] + r*g1y) * inv1;
                }
            }
            {   // channel 1 (reuse window registers)
                ldrow(su1, qy-1, qx, A); ldrow(su1, qy, qx, B); ldrow(su1, qy+1, qx, C);
                #pragma unroll
                for (int j = 0; j < 4; ++j) {
                    float g2x = -A[j] + A[j+2] - 2.f*B[j] + 2.f*B[j+2] - C[j] + C[j+2];
                    float g2y = -A[j] - 2.f*A[j+1] - A[j+2] + C[j] + 2.f*C[j+1] + C[j+2];
                    float inv2 = 1.f / (1.f + r*(fabsf(g2x) + fabsf(g2y)));
                    rp20[j] = (rp20[j] + r*g2x) * inv2;
                    rp21[j] = (rp21[j] + r*g2y) * inv2;
                }
            }
            *(float4*)&sp10[qy][COFF+qx] = *(float4*)rp10;
            *(float4*)&sp11[qy][COFF+qx] = *(float4*)rp11;
            *(float4*)&sp20[qy][COFF+qx] = *(float4*)rp20;
            *(float4*)&sp21[qy][COFF+qx] = *(float4*)rp21;
        }
        __syncthreads();
    }

    // ---- write back interior straight from registers ----
    if (qy >= HALO && qy < HALO+TY && qx >= HALO && qx < HALO+TX) {
        int go = (oy + qy)*WW + (ox + qx);       // interior always in-image, 16B-aligned
        *(float4*)&u[pb + go]      = *(float4*)ru0;
        *(float4*)&u[pb + HW + go] = *(float4*)ru1;
        if (!LAST) {
            *(float4*)&p1[pb + go]      = *(float4*)rp10;
            *(float4*)&p1[pb + HW + go] = *(float4*)rp11;
            *(float4*)&p2[pb + go]      = *(float4*)rp20;
            *(float4*)&p2[pb + HW + go] = *(float4*)rp21;
        }
    }
}

extern "C" void kernel_launch(void* const* d_in, const int* in_sizes, int n_in,
                              void* d_out, int out_size, void* d_ws, size_t ws_size,
                              hipStream_t stream) {
    const float* xin = (const float*)d_in[0];
    const float* lam = (const float*)d_in[1];
    const float* tau = (const float*)d_in[2];
    const float* the = (const float*)d_in[3];
    float* u = (float*)d_out;              // u lives in d_out (B,2,H,W)

    float* ws = (float*)d_ws;
    float* p1 = ws;                        // B*2*HW
    float* p2 = ws + (size_t)BB*2*HW;      // B*2*HW
    float* gx = ws + (size_t)2*BB*2*HW;    // B*HW
    float* gy = gx + (size_t)BB*HW;        // B*HW
    float* rc = gy + (size_t)BB*HW;        // B*HW

    {
        dim3 blk(64, 4, 1);
        dim3 grd(WW/64, HH/4, BB);
        tvl1_init<<<grd, blk, 0, stream>>>(xin, u, p1, p2, gx, gy, rc);
    }

    dim3 blk(NTHR, 1, 1);
    dim3 grd(WW/TX, HH/TY, BB);            // 8 x 16 x 4 = 512 blocks = 2/CU
    const int NLAUNCH = N_ITER / FUSE;     // 5
    for (int j = 0; j < NLAUNCH; ++j) {
        if (j < NLAUNCH - 1)
            tvl1_fused<0><<<grd, blk, 0, stream>>>(u, p1, p2, gx, gy, rc, lam, tau, the);
        else
            tvl1_fused<1><<<grd, blk, 0, stream>>>(u, p1, p2, gx, gy, rc, lam, tau, the);
    }
}

// Round 8
// 97.184 us; speedup vs baseline: 1.8551x; 1.8551x over previous
//
#include <hip/hip_runtime.h>

#define HH 256
#define WW 256
#define BB 4
#define HW (HH*WW)
#define N_ITER 20
#define EPSV 1e-8f

#define FUSE 4
#define TILE 32
#define HALO (2*FUSE)            // 8
#define EXT  (TILE + 2*HALO)     // 48
#define EPAD 49                  // odd stride: conflict-free scalar pattern (A's layout)
#define NTHR 1024                // 16 waves -> 16 waves/CU at 1 block/CU
#define NPX  3                   // ceil(48*48 / 1024)

__device__ __forceinline__ float ldz(const float* __restrict__ p, int y, int x) {
    if ((unsigned)y < HH && (unsigned)x < WW) return p[y*WW + x];
    return 0.0f;
}
__device__ __forceinline__ float sobelXg(const float* __restrict__ p, int y, int x) {
    return -ldz(p,y-1,x-1) + ldz(p,y-1,x+1)
         - 2.0f*ldz(p,y,x-1) + 2.0f*ldz(p,y,x+1)
         - ldz(p,y+1,x-1) + ldz(p,y+1,x+1);
}
__device__ __forceinline__ float sobelYg(const float* __restrict__ p, int y, int x) {
    return -ldz(p,y-1,x-1) - 2.0f*ldz(p,y-1,x) - ldz(p,y-1,x+1)
          + ldz(p,y+1,x-1) + 2.0f*ldz(p,y+1,x) + ldz(p,y+1,x+1);
}

__global__ void tvl1_init(const float* __restrict__ xin, float* __restrict__ u,
                          float* __restrict__ p1, float* __restrict__ p2,
                          float* __restrict__ gx, float* __restrict__ gy,
                          float* __restrict__ rc) {
    int x = blockIdx.x*blockDim.x + threadIdx.x;
    int y = blockIdx.y*blockDim.y + threadIdx.y;
    int b = blockIdx.z;
    int idx = y*WW + x;
    int pb = b*2*HW;
    const float* im1 = xin + pb + HW;     // channel 1
    float i1 = im1[idx];
    rc[b*HW + idx] = i1 - xin[pb + idx];  // im1 - im0
    gx[b*HW + idx] = sobelXg(im1, y, x);
    gy[b*HW + idx] = sobelYg(im1, y, x);
    u[pb + idx] = 0.0f;  u[pb + HW + idx] = 0.0f;
    p1[pb + idx] = 0.0f; p1[pb + HW + idx] = 0.0f;
    p2[pb + idx] = 0.0f; p2[pb + HW + idx] = 0.0f;
}

template<int LAST>
__global__ __launch_bounds__(NTHR)
void tvl1_fused(float* __restrict__ u,
                float* __restrict__ p1, float* __restrict__ p2,
                const float* __restrict__ gxc, const float* __restrict__ gyc,
                const float* __restrict__ rcc,
                const float* __restrict__ lam, const float* __restrict__ tau,
                const float* __restrict__ the) {
    // Only neighbor-visible fields live in LDS (6 * 48*49*4B = 56.4 KB).
    __shared__ float su0[EXT][EPAD], su1[EXT][EPAD];
    __shared__ float sp10[EXT][EPAD], sp11[EXT][EPAD];
    __shared__ float sp20[EXT][EPAD], sp21[EXT][EPAD];

    const int tid = threadIdx.x;
    const int b  = blockIdx.z;
    const int ox = blockIdx.x*TILE - HALO;
    const int oy = blockIdx.y*TILE - HALO;
    const int pb = b*2*HW, cb = b*HW;
    const float theta = the[0];
    const float tl = theta * lam[0];
    const float r = tau[0] / theta;

    // ---- static slot <-> pixel mapping ----
    int lys[NPX], lxs[NPX];
    bool act[NPX], upd[NPX];
    #pragma unroll
    for (int k = 0; k < NPX; ++k) {
        int i = tid + k*NTHR;
        act[k] = (i < EXT*EXT);
        int ii = act[k] ? i : 0;
        int ly = ii / EXT, lx = ii - ly*EXT;
        lys[k] = ly; lxs[k] = lx;
        bool img = ((unsigned)(oy+ly) < HH) && ((unsigned)(ox+lx) < WW);
        // update set: in-image (SAME-pad zeros stay zero) and stencil-readable.
        // No ring shrinking needed: stale ring-h values are never read by any
        // pixel that remains valid (1 ring per half-step, halo = 8 = NH).
        upd[k] = act[k] && img &&
                 (ly >= 1) && (ly < EXT-1) && (lx >= 1) && (lx < EXT-1);
        act[k] = act[k] && img;   // stage real data only for in-image slots
    }

    // ---- per-slot register state ----
    float ru0[NPX], ru1[NPX], rp10[NPX], rp11[NPX], rp20[NPX], rp21[NPX];
    float rgx[NPX], rgy[NPX], rrc[NPX];

    // ---- stage: regs hold pointwise state; LDS gets neighbor-visible copies ----
    #pragma unroll
    for (int k = 0; k < NPX; ++k) {
        int ly = lys[k], lx = lxs[k];
        int gi = (oy+ly)*WW + (ox+lx);
        float v0=0.f, v1=0.f, w0=0.f, w1=0.f, w2=0.f, w3=0.f, a=0.f, c=0.f, d=0.f;
        if (act[k]) {
            v0 = u[pb + gi];       v1 = u[pb + HW + gi];
            w0 = p1[pb + gi];      w1 = p1[pb + HW + gi];
            w2 = p2[pb + gi];      w3 = p2[pb + HW + gi];
            a  = gxc[cb + gi];     c  = gyc[cb + gi];     d = rcc[cb + gi];
        }
        ru0[k]=v0; ru1[k]=v1; rp10[k]=w0; rp11[k]=w1; rp20[k]=w2; rp21[k]=w3;
        rgx[k]=a; rgy[k]=c; rrc[k]=d;
        if (k < 2 || tid < EXT*EXT - 2*NTHR) {   // all slots with i < EXT*EXT
            su0[ly][lx]=v0;  su1[ly][lx]=v1;
            sp10[ly][lx]=w0; sp11[ly][lx]=w1;
            sp20[ly][lx]=w2; sp21[ly][lx]=w3;
        }
    }
    __syncthreads();

    #pragma unroll
    for (int it = 0; it < FUSE; ++it) {
        // ---- u half-step: pointwise u/gx/gy/rc from regs, p taps from LDS ----
        #pragma unroll
        for (int k = 0; k < NPX; ++k) {
            if (upd[k]) {
                int ly = lys[k], lx = lxs[k];
                // SBX(sp10): 6 taps          SBY(sp20): 6 taps
                float x0 = (sp10[ly-1][lx+1] - sp10[ly-1][lx-1])
                         + 2.f*(sp10[ly][lx+1] - sp10[ly][lx-1])
                         + (sp10[ly+1][lx+1] - sp10[ly+1][lx-1]);
                float y0 = (sp20[ly+1][lx-1] - sp20[ly-1][lx-1])
                         + 2.f*(sp20[ly+1][lx] - sp20[ly-1][lx])
                         + (sp20[ly+1][lx+1] - sp20[ly-1][lx+1]);
                float x1 = (sp11[ly-1][lx+1] - sp11[ly-1][lx-1])
                         + 2.f*(sp11[ly][lx+1] - sp11[ly][lx-1])
                         + (sp11[ly+1][lx+1] - sp11[ly+1][lx-1]);
                float y1 = (sp21[ly+1][lx-1] - sp21[ly-1][lx-1])
                         + 2.f*(sp21[ly+1][lx] - sp21[ly-1][lx])
                         + (sp21[ly+1][lx+1] - sp21[ly-1][lx+1]);
                float g_x = rgx[k], g_y = rgy[k];
                float ng  = g_x*g_x + g_y*g_y + EPSV;
                float rho = rrc[k] + g_x*ru0[k] + g_y*ru1[k];
                float th  = tl * ng;
                float sgn = (rho > 0.f) ? 1.f : ((rho < 0.f) ? -1.f : 0.f);
                float dd  = (fabsf(rho) < th) ? (rho / ng) : (tl * sgn);
                ru0[k] = ru0[k] - dd*g_x + theta*(x0 + y0);
                ru1[k] = ru1[k] - dd*g_y + theta*(x1 + y1);
                su0[ly][lx] = ru0[k];
                su1[ly][lx] = ru1[k];
            }
        }
        __syncthreads();

        if (LAST && it == FUSE-1) break;    // 20th p-update never feeds the output

        // ---- p half-step: pointwise p from regs, u taps from LDS (8-tap union) ----
        #pragma unroll
        for (int k = 0; k < NPX; ++k) {
            if (upd[k]) {
                int ly = lys[k], lx = lxs[k];
                {   // channel 0: 8 unique taps serve both SBX and SBY
                    float a_ = su0[ly-1][lx-1], b_ = su0[ly-1][lx], c_ = su0[ly-1][lx+1];
                    float d_ = su0[ly  ][lx-1],                      e_ = su0[ly  ][lx+1];
                    float f_ = su0[ly+1][lx-1], g_ = su0[ly+1][lx], h_ = su0[ly+1][lx+1];
                    float g1x = (c_ - a_) + 2.f*(e_ - d_) + (h_ - f_);
                    float g1y = (f_ - a_) + 2.f*(g_ - b_) + (h_ - c_);
                    float inv1 = 1.f / (1.f + r*(fabsf(g1x) + fabsf(g1y)));
                    rp10[k] = (rp10[k] + r*g1x) * inv1;
                    rp11[k] = (rp11[k] + r*g1y) * inv1;
                }
                {   // channel 1
                    float a_ = su1[ly-1][lx-1], b_ = su1[ly-1][lx], c_ = su1[ly-1][lx+1];
                    float d_ = su1[ly  ][lx-1],                      e_ = su1[ly  ][lx+1];
                    float f_ = su1[ly+1][lx-1], g_ = su1[ly+1][lx], h_ = su1[ly+1][lx+1];
                    float g2x = (c_ - a_) + 2.f*(e_ - d_) + (h_ - f_);
                    float g2y = (f_ - a_) + 2.f*(g_ - b_) + (h_ - c_);
                    float inv2 = 1.f / (1.f + r*(fabsf(g2x) + fabsf(g2y)));
                    rp20[k] = (rp20[k] + r*g2x) * inv2;
                    rp21[k] = (rp21[k] + r*g2y) * inv2;
                }
                sp10[ly][lx] = rp10[k];
                sp11[ly][lx] = rp11[k];
                sp20[ly][lx] = rp20[k];
                sp21[ly][lx] = rp21[k];
            }
        }
        __syncthreads();
    }

    // ---- write back interior straight from registers ----
    #pragma unroll
    for (int k = 0; k < NPX; ++k) {
        int ly = lys[k], lx = lxs[k];
        if (upd[k] && ly >= HALO && ly < HALO+TILE && lx >= HALO && lx < HALO+TILE) {
            int go = (oy + ly)*WW + (ox + lx);
            u[pb + go]      = ru0[k];
            u[pb + HW + go] = ru1[k];
            if (!LAST) {
                p1[pb + go]      = rp10[k];
                p1[pb + HW + go] = rp11[k];
                p2[pb + go]      = rp20[k];
                p2[pb + HW + go] = rp21[k];
            }
        }
    }
}

extern "C" void kernel_launch(void* const* d_in, const int* in_sizes, int n_in,
                              void* d_out, int out_size, void* d_ws, size_t ws_size,
                              hipStream_t stream) {
    const float* xin = (const float*)d_in[0];
    const float* lam = (const float*)d_in[1];
    const float* tau = (const float*)d_in[2];
    const float* the = (const float*)d_in[3];
    float* u = (float*)d_out;              // u lives in d_out (B,2,H,W)

    float* ws = (float*)d_ws;
    float* p1 = ws;                        // B*2*HW
    float* p2 = ws + (size_t)BB*2*HW;      // B*2*HW
    float* gx = ws + (size_t)2*BB*2*HW;    // B*HW
    float* gy = gx + (size_t)BB*HW;        // B*HW
    float* rc = gy + (size_t)BB*HW;        // B*HW

    {
        dim3 blk(64, 4, 1);
        dim3 grd(WW/64, HH/4, BB);
        tvl1_init<<<grd, blk, 0, stream>>>(xin, u, p1, p2, gx, gy, rc);
    }

    dim3 blk(NTHR, 1, 1);
    dim3 grd(WW/TILE, HH/TILE, BB);        // 8 x 8 x 4 = 256 blocks = 1/CU
    const int NLAUNCH = N_ITER / FUSE;     // 5
    for (int j = 0; j < NLAUNCH; ++j) {
        if (j < NLAUNCH - 1)
            tvl1_fused<0><<<grd, blk, 0, stream>>>(u, p1, p2, gx, gy, rc, lam, tau, the);
        else
            tvl1_fused<1><<<grd, blk, 0, stream>>>(u, p1, p2, gx, gy, rc, lam, tau, the);
    }
}